// Round 9
// baseline (60.839 us; speedup 1.0000x reference)
//
#include <hip/hip_runtime.h>

// Problem constants (from reference)
#define TOK_CODE_START 256
#define TOK_CODE_END   257
#define TOK_MEM        258
#define ADDR_KEY       206
#define MEM_STORE      455

constexpr int Bb = 16;
constexpr int Ss = 8192;
constexpr int DM = 512;

typedef float f32x4 __attribute__((ext_vector_type(4)));

// ---------------------------------------------------------------------------
// Kernel 1: per-row scan. One block per batch row, 1024 threads (16 waves),
// 8 tokens per thread. Wave-level shuffle scan + one LDS round for the 16
// wave carries. Packs per (b,s):
//   bits[0..8]=token  bit9=valid  bit10=mem_flag  bits[11..]=addr
// into one u32 in d_ws.
// ---------------------------------------------------------------------------
__global__ __launch_bounds__(1024) void vm_scan_kernel(
    const int* __restrict__ tok,
    const int* __restrict__ mhe_p,
    unsigned int* __restrict__ ws)
{
    const int b = blockIdx.x;
    const int t = threadIdx.x;              // 0..1023
    const int lane = t & 63;
    const int wid = t >> 6;                 // 0..15
    const int mhe = mhe_p[0];
    const int* row = tok + b * Ss;
    const int base = t * 8;

    int toks[8];
    int4 v0 = reinterpret_cast<const int4*>(row + base)[0];
    int4 v1 = reinterpret_cast<const int4*>(row + base)[1];
    toks[0] = v0.x; toks[1] = v0.y; toks[2] = v0.z; toks[3] = v0.w;
    toks[4] = v1.x; toks[5] = v1.y; toks[6] = v1.z; toks[7] = v1.w;

    // per-thread chunk summaries
    int lmax = -1;      // max index of CODE_START in my 8 (-1 if none)
    int lend = Ss;      // first index of CODE_END in my 8 (Ss if none)
    #pragma unroll
    for (int k = 0; k < 8; ++k) {
        int idx = base + k;
        if (toks[k] == TOK_CODE_START) lmax = idx;             // idx increasing
        if (toks[k] == TOK_CODE_END && lend == Ss) lend = idx; // first
    }

    // wave inclusive max-scan of lmax (6 shuffle steps, no barriers)
    #pragma unroll
    for (int off = 1; off < 64; off <<= 1) {
        int u = __shfl_up(lmax, off);
        if (lane >= off && u > lmax) lmax = u;
    }
    // exclusive version for this thread
    int excl = __shfl_up(lmax, 1);
    if (lane == 0) excl = -1;

    // wave min-reduce of lend (all lanes get the wave min)
    #pragma unroll
    for (int off = 32; off > 0; off >>= 1) {
        int u = __shfl_xor(lend, off);
        if (u < lend) lend = u;
    }

    __shared__ int wmax[16];   // per-wave inclusive total (lane 63's value)
    __shared__ int wend[16];   // per-wave min first-end
    if (lane == 63) wmax[wid] = lmax;
    if (lane == 0)  wend[wid] = lend;
    __syncthreads();

    int carry = -1;
    #pragma unroll
    for (int j = 0; j < 16; ++j)
        if (j < wid && wmax[j] > carry) carry = wmax[j];
    int end_idx = Ss;
    #pragma unroll
    for (int j = 0; j < 16; ++j)
        if (wend[j] < end_idx) end_idx = wend[j];

    int run = (carry > excl) ? carry : excl;   // latest start strictly before my chunk

    unsigned int pk[8];
    #pragma unroll
    for (int k = 0; k < 8; ++k) {
        int idx = base + k;
        int tv = toks[k];
        if (tv == TOK_CODE_START) run = idx;   // inclusive cummax update
        int cs = run;
        int addr = idx - cs - 1;
        bool valid = (cs >= 0) && (idx < end_idx) && (tv < 256) && (addr >= 0);
        bool memf  = (tv == TOK_MEM) && (idx < mhe);
        unsigned int w = (unsigned int)tv;                       // bits 0..8
        if (valid) w |= (1u << 9) | ((unsigned int)addr << 11);
        if (memf)  w |= (1u << 10);
        pk[k] = w;
    }
    uint4* wr = reinterpret_cast<uint4*>(ws + b * Ss + base);
    wr[0] = make_uint4(pk[0], pk[1], pk[2], pk[3]);
    wr[1] = make_uint4(pk[4], pk[5], pk[6], pk[7]);
}

// ---------------------------------------------------------------------------
// Kernel 2: gather + mask overwrite, grid-stride, nt stores (R3 champion).
// SINGLE CHANGE vs R3: the 32 iterations are processed as 8 groups of 4
// with the dependent chain batched — 4 independent ws loads issued together,
// then 4 independent embed loads, then 4 mask+stores. Converts the
// ws -> tk -> embed -> store serial latency (~400-500 cy/iter if the
// compiler doesn't pipeline) into 4-way memory-level parallelism.
// ---------------------------------------------------------------------------
__global__ __launch_bounds__(256) void vm_gather_kernel(
    const f32x4* __restrict__ emb,
    const unsigned int* __restrict__ ws,
    f32x4* __restrict__ out)
{
    constexpr int STRIDE = 2048 * 256;       // grid size (fixed launch)
    constexpr int GROUPS = 8;                // 8 groups x 4 iters x STRIDE = 16,777,216
    const int tid = blockIdx.x * 256 + threadIdx.x;

    #pragma unroll 1
    for (int g = 0; g < GROUPS; ++g) {
        const int w0 = tid + (g * 4) * STRIDE;
        const int w1 = w0 + STRIDE;
        const int w2 = w0 + 2 * STRIDE;
        const int w3 = w0 + 3 * STRIDE;

        // --- 4 independent ws loads (batch 1) ---
        unsigned int pw0 = ws[w0 >> 7];
        unsigned int pw1 = ws[w1 >> 7];
        unsigned int pw2 = ws[w2 >> 7];
        unsigned int pw3 = ws[w3 >> 7];

        // --- 4 independent embed loads (batch 2) ---
        f32x4 v0 = emb[(int)(pw0 & 511u) * (DM / 4) + (w0 & 127)];
        f32x4 v1 = emb[(int)(pw1 & 511u) * (DM / 4) + (w1 & 127)];
        f32x4 v2 = emb[(int)(pw2 & 511u) * (DM / 4) + (w2 & 127)];
        f32x4 v3 = emb[(int)(pw3 & 511u) * (DM / 4) + (w3 & 127)];

        // --- mask + store x4 ---
        #pragma unroll
        for (int j = 0; j < 4; ++j) {
            unsigned int pw = (j == 0) ? pw0 : (j == 1) ? pw1 : (j == 2) ? pw2 : pw3;
            int w = (j == 0) ? w0 : (j == 1) ? w1 : (j == 2) ? w2 : w3;
            f32x4 v = (j == 0) ? v0 : (j == 1) ? v1 : (j == 2) ? v2 : v3;
            unsigned int flags = pw >> 9;
            if (flags) {                     // ~wave-uniform, mostly false
                bool valid = (flags & 1u) != 0u;
                bool memf  = (flags & 2u) != 0u;
                int addr = (int)(flags >> 2);
                int p0 = ADDR_KEY      + (addr & 15);
                int p1 = ADDR_KEY + 16 + ((addr >> 4) & 15);
                int p2 = ADDR_KEY + 32 + ((addr >> 8) & 15);
                int d0 = (w & 127) << 2;
                #pragma unroll
                for (int jj = 0; jj < 4; ++jj) {
                    int d = d0 + jj;
                    if ((valid && (d == p0 || d == p1 || d == p2)) ||
                        (memf && d == MEM_STORE)) v[jj] = 1.0f;
                }
            }
            __builtin_nontemporal_store(v, &out[w]);
        }
    }
}

extern "C" void kernel_launch(void* const* d_in, const int* in_sizes, int n_in,
                              void* d_out, int out_size, void* d_ws, size_t ws_size,
                              hipStream_t stream) {
    const int* tok = (const int*)d_in[0];
    const float* emb = (const float*)d_in[1];
    const int* mhe = (const int*)d_in[2];
    unsigned int* ws = (unsigned int*)d_ws;   // needs Bb*Ss*4 = 512 KiB
    f32x4* out = (f32x4*)d_out;

    vm_scan_kernel<<<Bb, 1024, 0, stream>>>(tok, mhe, ws);
    vm_gather_kernel<<<2048, 256, 0, stream>>>((const f32x4*)emb, ws, out);
}